// Round 9
// baseline (703.619 us; speedup 1.0000x reference)
//
#include <hip/hip_runtime.h>
#include <hip/hip_bf16.h>

#define DIN 32
#define HC  64   // H*C
#define NPB 512  // nodes per bucket (dst >> 9)

using bf = __hip_bfloat16;
static __device__ __forceinline__ float b2f(bf v){ return __bfloat162float(v); }

// ---- bucketed CSR build (R7 structure; R9: uint32 packed pair buffer) --

__global__ void k_bhist(const int* __restrict__ edge, const int* __restrict__ batch,
                        int E, int N, int NB, int* __restrict__ bc, int* __restrict__ gcnt){
  __shared__ int lh[1024];
  int t = threadIdx.x;
  for (int i = t; i < NB; i += blockDim.x) lh[i] = 0;
  __syncthreads();
  int M = max(E, N);
  int stride = gridDim.x*blockDim.x;
  for (int i = blockIdx.x*blockDim.x + t; i < M; i += stride){
    if (i < E) atomicAdd(&lh[edge[E + i] >> 9], 1);
    if (i < N) atomicAdd(&gcnt[batch[i]], 1);   // sorted batch -> wave-coalesced
  }
  __syncthreads();
  for (int i = t; i < NB; i += blockDim.x){ int c = lh[i]; if (c) atomicAdd(&bc[i], c); }
}

__global__ void k_bscan(const int* __restrict__ bc, int NB, int E, int N,
                        int* __restrict__ bbase, int* __restrict__ bcur,
                        int* __restrict__ sbase, int* __restrict__ offs){
  __shared__ int s[1024];
  int t = threadIdx.x;
  int mine = (t < NB) ? bc[t] : 0;
  s[t] = mine; __syncthreads();
  for (int d = 1; d < 1024; d <<= 1){
    int v = (t >= d) ? s[t-d] : 0;
    __syncthreads();
    s[t] += v;
    __syncthreads();
  }
  int excl = s[t] - mine;
  if (t < NB){
    bbase[t] = excl;
    bcur[t]  = excl;
    sbase[t] = excl + t*NPB;   // preceding buckets full -> +t*NPB self-loops
  }
  if (t == 0){ bbase[NB] = E; offs[N] = E + N; }
}

// pack (src, local dst) into uint32: src<<9 | dl. Valid for N < 2^23... here
// N=100k < 2^17 so src<<9 < 2^26. Halves buf traffic vs uint2.
__global__ void k_bscatter(const int* __restrict__ edge, int E, int NB,
                           int* __restrict__ bcur, unsigned* __restrict__ buf){
  __shared__ int lcnt[1024];
  __shared__ int lcur[1024];
  int t = threadIdx.x;
  int chunk = (E + gridDim.x - 1) / gridDim.x;
  int beg = blockIdx.x*chunk, end = min(E, beg + chunk);
  for (int i = t; i < NB; i += blockDim.x) lcnt[i] = 0;
  __syncthreads();
  for (int i = beg + t; i < end; i += blockDim.x)
    atomicAdd(&lcnt[edge[E + i] >> 9], 1);
  __syncthreads();
  for (int i = t; i < NB; i += blockDim.x){
    int c = lcnt[i];
    lcur[i] = c ? atomicAdd(&bcur[i], c) : 0;
  }
  __syncthreads();
  for (int i = beg + t; i < end; i += blockDim.x){
    int sN = edge[i], d = edge[E + i];
    int pos = atomicAdd(&lcur[d >> 9], 1);
    buf[pos] = ((unsigned)sN << 9) | (unsigned)(d & 511);
  }
}

__global__ void k_bbuild(const unsigned* __restrict__ buf, const int* __restrict__ bbase,
                         const int* __restrict__ sbase, int N,
                         int* __restrict__ offs, int* __restrict__ srcs){
  __shared__ int s[NPB];
  __shared__ int cur[NPB];
  int b = blockIdx.x, t = threadIdx.x;
  int base = b << 9;
  int nn = min(NPB, N - base);
  int sbeg = bbase[b], send = bbase[b+1];
  int sb = sbase[b];
  s[t] = (t < nn) ? 1 : 0;                 // self-loop seed
  __syncthreads();
  for (int i = sbeg + t; i < send; i += NPB)
    atomicAdd(&s[buf[i] & 511u], 1);
  __syncthreads();
  int c0 = s[t];
  __syncthreads();
  for (int d = 1; d < NPB; d <<= 1){
    int v = (t >= d) ? s[t-d] : 0;
    __syncthreads();
    s[t] += v;
    __syncthreads();
  }
  int start = s[t] - c0;
  if (t < nn){
    offs[base + t] = sb + start;
    srcs[sb + start] = base + t;           // self-loop
    cur[t] = start + 1;
  }
  __syncthreads();
  for (int i = sbeg + t; i < send; i += NPB){
    unsigned v = buf[i];
    int pos = atomicAdd(&cur[v & 511u], 1);
    srcs[sb + pos] = (int)(v >> 9);
  }
}

// ---- GAT node transform v2 (R8, working): W in VGPRs, x broadcast ------

template<int K, bool BF16IN>
__global__ void k_transform(const void* __restrict__ xin_,
                            const float* __restrict__ W,
                            const float* __restrict__ a_s,
                            const float* __restrict__ a_d,
                            bf* __restrict__ feat,
                            float* __restrict__ asrc, float* __restrict__ adst, int N){
  int t = threadIdx.x, lane = t & 63, wid = t >> 6;
  float wreg[K];
  #pragma unroll
  for (int k = 0; k < K; k++) wreg[k] = W[k*HC + lane];   // coalesced 256B per k
  float as_l = a_s[lane], ad_l = a_d[lane];
  int gw = blockIdx.x*(blockDim.x >> 6) + wid;
  int nw = gridDim.x*(blockDim.x >> 6);
  for (int n = gw; n < N; n += nw){
    float acc = 0.f;
    if (BF16IN){
      const bf* xr = (const bf*)xin_ + (size_t)n*K;
      #pragma unroll
      for (int k = 0; k < K; k += 8){
        uint4 d = *(const uint4*)(xr + k);                // same-addr broadcast
        acc = fmaf(__int_as_float((int)(d.x << 16)),         wreg[k+0], acc);
        acc = fmaf(__int_as_float((int)(d.x & 0xffff0000u)), wreg[k+1], acc);
        acc = fmaf(__int_as_float((int)(d.y << 16)),         wreg[k+2], acc);
        acc = fmaf(__int_as_float((int)(d.y & 0xffff0000u)), wreg[k+3], acc);
        acc = fmaf(__int_as_float((int)(d.z << 16)),         wreg[k+4], acc);
        acc = fmaf(__int_as_float((int)(d.z & 0xffff0000u)), wreg[k+5], acc);
        acc = fmaf(__int_as_float((int)(d.w << 16)),         wreg[k+6], acc);
        acc = fmaf(__int_as_float((int)(d.w & 0xffff0000u)), wreg[k+7], acc);
      }
    } else {
      const float* xr = (const float*)xin_ + (size_t)n*K;
      #pragma unroll
      for (int k = 0; k < K; k += 4){
        float4 xv = *(const float4*)(xr + k);             // same-addr broadcast
        acc = fmaf(xv.x, wreg[k+0], acc);
        acc = fmaf(xv.y, wreg[k+1], acc);
        acc = fmaf(xv.z, wreg[k+2], acc);
        acc = fmaf(xv.w, wreg[k+3], acc);
      }
    }
    feat[((size_t)n << 6) + lane] = __float2bfloat16(acc);
    float ps = acc*as_l, pd = acc*ad_l;
    #pragma unroll
    for (int d = 1; d < 16; d <<= 1){ ps += __shfl_xor(ps, d); pd += __shfl_xor(pd, d); }
    if ((lane & 15) == 0){
      asrc[n*4 + (lane>>4)] = ps;
      adst[n*4 + (lane>>4)] = pd;
    }
  }
}

// ---- softmax-aggregate v5: 8 edges per iteration -----------------------
// lane = (channel-octet o=lane&7, edge-of-8 q=lane>>3). Per iter per lane:
// 1 ds_read_b64 (w for my head, src bits), 1 global dwordx4 (8 bf16 ch =
// 1 KB/wave, coalescing sweet spot), 8 fma, 1 den add. Addr calc amortized
// 8x vs v3. Fold q via shfl_xor(8/16/32); lanes 0..7 write 16 B each.
// LDS pad [68]: 32 distinct float2 reads/iter -> 2 words/bank (free, m136).
// Softmax w/o max safe: logits ~|3|, den>0 (self-loop).

template<bool FINAL>
__global__ void k_aggregate(const int* __restrict__ offs, const int* __restrict__ srcs,
                            const bf* __restrict__ feat,
                            const float* __restrict__ asrc, const float* __restrict__ adst,
                            const float* __restrict__ bias,
                            bf* __restrict__ out,
                            const int* __restrict__ batch,
                            float* __restrict__ pooled, int N){
  __shared__ float2 lwh[4][4][68];         // [wave][head][edge slot(+pad)]
  int t = threadIdx.x, lane = t & 63, wid = t >> 6;
  int n = blockIdx.x*(blockDim.x >> 6) + wid;
  if (n >= N) return;
  int o = lane & 7, q = lane >> 3, h = o >> 1;
  const float4 adv = *(const float4*)(adst + (size_t)n*4);
  int beg = offs[n], end = offs[n+1];
  float a0=0.f,a1=0.f,a2=0.f,a3=0.f,a4=0.f,a5=0.f,a6=0.f,a7=0.f,den=0.f;
  const float2* lp = &lwh[wid][h][q];
  for (int j0 = beg; j0 < end; j0 += 64){
    int m = end - j0; if (m > 64) m = 64;
    // phase A: lane = edge (pad lanes write w=0, s=0 -> safe dummy rows)
    int sv = (lane < m) ? srcs[j0 + lane] : 0;
    float4 av = *(const float4*)(asrc + (size_t)sv*4);
    float z = (lane < m) ? 1.f : 0.f;
    float e0 = av.x + adv.x; e0 = (e0>0.f)?e0:0.2f*e0;
    float e1 = av.y + adv.y; e1 = (e1>0.f)?e1:0.2f*e1;
    float e2 = av.z + adv.z; e2 = (e2>0.f)?e2:0.2f*e2;
    float e3 = av.w + adv.w; e3 = (e3>0.f)?e3:0.2f*e3;
    float sb = __int_as_float(sv);
    lwh[wid][0][lane] = make_float2(z*__expf(e0), sb);
    lwh[wid][1][lane] = make_float2(z*__expf(e1), sb);
    lwh[wid][2][lane] = make_float2(z*__expf(e2), sb);
    lwh[wid][3][lane] = make_float2(z*__expf(e3), sb);
    // phase B: 8 edges per iteration (slots jj+q <= 63 always written)
    #pragma unroll 2
    for (int jj = 0; jj < m; jj += 8){
      float2 rec = lp[jj];                 // (w for my head, src bits)
      int s = __float_as_int(rec.y);
      uint4 d4 = ((const uint4*)(feat + ((size_t)s << 6)))[o];
      float w = rec.x;
      a0 = fmaf(w, __int_as_float((int)(d4.x << 16)),         a0);
      a1 = fmaf(w, __int_as_float((int)(d4.x & 0xffff0000u)), a1);
      a2 = fmaf(w, __int_as_float((int)(d4.y << 16)),         a2);
      a3 = fmaf(w, __int_as_float((int)(d4.y & 0xffff0000u)), a3);
      a4 = fmaf(w, __int_as_float((int)(d4.z << 16)),         a4);
      a5 = fmaf(w, __int_as_float((int)(d4.z & 0xffff0000u)), a5);
      a6 = fmaf(w, __int_as_float((int)(d4.w << 16)),         a6);
      a7 = fmaf(w, __int_as_float((int)(d4.w & 0xffff0000u)), a7);
      den += w;
    }
  }
  #pragma unroll
  for (int d = 8; d < 64; d <<= 1){
    a0 += __shfl_xor(a0,d); a1 += __shfl_xor(a1,d);
    a2 += __shfl_xor(a2,d); a3 += __shfl_xor(a3,d);
    a4 += __shfl_xor(a4,d); a5 += __shfl_xor(a5,d);
    a6 += __shfl_xor(a6,d); a7 += __shfl_xor(a7,d);
    den += __shfl_xor(den,d);
  }
  if (lane < 8){
    int c0 = lane << 3;
    float inv = 1.f/den;
    float4 b0 = *(const float4*)(bias + c0);
    float4 b1 = *(const float4*)(bias + c0 + 4);
    float r0 = fmaf(a0, inv, b0.x), r1 = fmaf(a1, inv, b0.y);
    float r2 = fmaf(a2, inv, b0.z), r3 = fmaf(a3, inv, b0.w);
    float r4 = fmaf(a4, inv, b1.x), r5 = fmaf(a5, inv, b1.y);
    float r6 = fmaf(a6, inv, b1.z), r7 = fmaf(a7, inv, b1.w);
    r0=(r0>0.f)?r0:expm1f(r0); r1=(r1>0.f)?r1:expm1f(r1);
    r2=(r2>0.f)?r2:expm1f(r2); r3=(r3>0.f)?r3:expm1f(r3);
    r4=(r4>0.f)?r4:expm1f(r4); r5=(r5>0.f)?r5:expm1f(r5);
    r6=(r6>0.f)?r6:expm1f(r6); r7=(r7>0.f)?r7:expm1f(r7);
    if (FINAL){
      float* pg = pooled + (size_t)batch[n]*HC + c0;
      atomicAdd(pg+0,r0); atomicAdd(pg+1,r1); atomicAdd(pg+2,r2); atomicAdd(pg+3,r3);
      atomicAdd(pg+4,r4); atomicAdd(pg+5,r5); atomicAdd(pg+6,r6); atomicAdd(pg+7,r7);
    } else {
      bf tmp[8];
      tmp[0]=__float2bfloat16(r0); tmp[1]=__float2bfloat16(r1);
      tmp[2]=__float2bfloat16(r2); tmp[3]=__float2bfloat16(r3);
      tmp[4]=__float2bfloat16(r4); tmp[5]=__float2bfloat16(r5);
      tmp[6]=__float2bfloat16(r6); tmp[7]=__float2bfloat16(r7);
      *(uint4*)(out + ((size_t)n << 6) + c0) = *(const uint4*)tmp;
    }
  }
}

// ---- head: mean-pool already summed; MLPs. fp32 output -----------------

__global__ void k_final(const float* __restrict__ pooled, const int* __restrict__ gcnt,
                        const float* __restrict__ guid,
                        const float* __restrict__ Wg, const float* __restrict__ bg,
                        const float* __restrict__ Wu, const float* __restrict__ bu,
                        const float* __restrict__ Wo, const float* __restrict__ bo,
                        float* __restrict__ outp, int G){
  __shared__ float sWg[HC*16], sWo[16*7], sbg[16], sWu[16], sbu[16], sbo[7];
  int t = threadIdx.x;
  for (int i = t; i < HC*16; i += blockDim.x) sWg[i] = Wg[i];
  for (int i = t; i < 16*7;  i += blockDim.x) sWo[i] = Wo[i];
  if (t < 16){ sbg[t] = bg[t]; sWu[t] = Wu[t]; sbu[t] = bu[t]; }
  if (t < 7) sbo[t] = bo[t];
  __syncthreads();
  int g = blockIdx.x*blockDim.x + t;
  if (g >= G) return;
  float inv = 1.f / fmaxf((float)gcnt[g], 1.f);
  float v[16];
  #pragma unroll
  for (int j = 0; j < 16; j++) v[j] = sbg[j];
  for (int c = 0; c < HC; c++){
    float pc = pooled[g*HC + c] * inv;
    #pragma unroll
    for (int j = 0; j < 16; j++) v[j] = fmaf(pc, sWg[c*16 + j], v[j]);
  }
  float gd = guid[g];
  #pragma unroll
  for (int j = 0; j < 16; j++){
    float u = fmaf(gd, sWu[j], sbu[j]);
    v[j] += (u > 0.f) ? u : 0.f;
  }
  #pragma unroll
  for (int k = 0; k < 7; k++){
    float o = sbo[k];
    #pragma unroll
    for (int j = 0; j < 16; j++) o = fmaf(v[j], sWo[j*7 + k], o);
    outp[g*7 + k] = o;
  }
}

// ---- launch ------------------------------------------------------------

extern "C" void kernel_launch(void* const* d_in, const int* in_sizes, int n_in,
                              void* d_out, int out_size, void* d_ws, size_t ws_size,
                              hipStream_t stream){
  const float* x    = (const float*)d_in[0];
  const int*   edge = (const int*)d_in[1];
  const int*   batch= (const int*)d_in[2];
  const float* guid = (const float*)d_in[3];
  const float* W1   = (const float*)d_in[4];
  const float* as1  = (const float*)d_in[5];
  const float* ad1  = (const float*)d_in[6];
  const float* b1   = (const float*)d_in[7];
  const float* W2   = (const float*)d_in[8];
  const float* as2  = (const float*)d_in[9];
  const float* ad2  = (const float*)d_in[10];
  const float* b2   = (const float*)d_in[11];
  const float* Wg   = (const float*)d_in[12];
  const float* bg   = (const float*)d_in[13];
  const float* Wu   = (const float*)d_in[14];
  const float* bu   = (const float*)d_in[15];
  const float* Wo   = (const float*)d_in[16];
  const float* bo   = (const float*)d_in[17];

  const int N = in_sizes[0] / DIN;
  const int E = in_sizes[1] / 2;
  const int G = in_sizes[3];
  const int NB = (N + NPB - 1) >> 9;

  char* p = (char*)d_ws;
  auto alloc = [&](size_t nbytes)->void*{
    void* r = (void*)p;
    p += ((nbytes + 255) & ~(size_t)255);
    return r;
  };
  char*  zstart = p;                       // bc|gcnt|pooled zeroed together
  int*   bc     = (int*)  alloc(1024*4);
  int*   gcnt   = (int*)  alloc((size_t)G*4);
  float* pooled = (float*)alloc((size_t)G*HC*4);
  size_t zbytes = (size_t)(p - zstart);
  int*   bbase  = (int*)  alloc(1025*4);
  int*   bcur   = (int*)  alloc(1024*4);
  int*   sbase  = (int*)  alloc(1025*4);
  int*   offs   = (int*)  alloc((size_t)(N+1)*4);
  int*   srcs   = (int*)  alloc(((size_t)E + N)*4);
  bf*    featA  = (bf*)   alloc((size_t)N*HC*2);   // bf16 feature tables
  bf*    featB  = (bf*)   alloc((size_t)N*HC*2);
  float* asrc   = (float*)alloc((size_t)N*4*4);
  float* adst   = (float*)alloc((size_t)N*4*4);
  size_t featBytes = (size_t)(((char*)asrc) - ((char*)featA));
  unsigned* buf = ((size_t)E*4 <= featBytes) ? (unsigned*)featA
                                             : (unsigned*)alloc((size_t)E*4);
  (void)ws_size; (void)n_in; (void)out_size;

  hipMemsetAsync(zstart, 0, zbytes, stream);

  k_bhist   <<<256, 256, 0, stream>>>(edge, batch, E, N, NB, bc, gcnt);
  k_bscan   <<<1, 1024, 0, stream>>>(bc, NB, E, N, bbase, bcur, sbase, offs);
  k_bscatter<<<256, 256, 0, stream>>>(edge, E, NB, bcur, buf);
  k_bbuild  <<<NB, NPB, 0, stream>>>(buf, bbase, sbase, N, offs, srcs);

  const int tpb = 256;
  const int nb  = (N + 3) / 4;             // aggregate: 1 node per wave
  const int ntb = 1024;                    // transform: grid-stride
  k_transform<DIN, false><<<ntb, tpb, 0, stream>>>(x, W1, as1, ad1, featA, asrc, adst, N);
  k_aggregate<false><<<nb, tpb, 0, stream>>>(offs, srcs, featA, asrc, adst, b1, featB, batch, pooled, N);
  k_transform<HC, true><<<ntb, tpb, 0, stream>>>(featB, W2, as2, ad2, featA, asrc, adst, N);
  k_aggregate<true><<<nb, tpb, 0, stream>>>(offs, srcs, featA, asrc, adst, b2, nullptr, batch, pooled, N);

  k_final<<<(G+255)/256, 256, 0, stream>>>(pooled, gcnt, guid, Wg, bg, Wu, bu, Wo, bo,
                                           (float*)d_out, G);
}

// Round 10
// 484.613 us; speedup vs baseline: 1.4519x; 1.4519x over previous
//
#include <hip/hip_runtime.h>
#include <hip/hip_bf16.h>

#define DIN 32
#define HC  64   // H*C
#define NPB 512  // nodes per bucket (dst >> 9)

using bf = __hip_bfloat16;
static __device__ __forceinline__ float b2f(bf v){ return __bfloat162float(v); }

// ---- bucketed CSR build (R7 structure; uint32 packed pair buffer) ------

__global__ void k_bhist(const int* __restrict__ edge, const int* __restrict__ batch,
                        int E, int N, int NB, int* __restrict__ bc, int* __restrict__ gcnt){
  __shared__ int lh[1024];
  int t = threadIdx.x;
  for (int i = t; i < NB; i += blockDim.x) lh[i] = 0;
  __syncthreads();
  int M = max(E, N);
  int stride = gridDim.x*blockDim.x;
  for (int i = blockIdx.x*blockDim.x + t; i < M; i += stride){
    if (i < E) atomicAdd(&lh[edge[E + i] >> 9], 1);
    if (i < N) atomicAdd(&gcnt[batch[i]], 1);   // sorted batch -> wave-coalesced
  }
  __syncthreads();
  for (int i = t; i < NB; i += blockDim.x){ int c = lh[i]; if (c) atomicAdd(&bc[i], c); }
}

__global__ void k_bscan(const int* __restrict__ bc, int NB, int E, int N,
                        int* __restrict__ bbase, int* __restrict__ bcur,
                        int* __restrict__ sbase, int* __restrict__ offs){
  __shared__ int s[1024];
  int t = threadIdx.x;
  int mine = (t < NB) ? bc[t] : 0;
  s[t] = mine; __syncthreads();
  for (int d = 1; d < 1024; d <<= 1){
    int v = (t >= d) ? s[t-d] : 0;
    __syncthreads();
    s[t] += v;
    __syncthreads();
  }
  int excl = s[t] - mine;
  if (t < NB){
    bbase[t] = excl;
    bcur[t]  = excl;
    sbase[t] = excl + t*NPB;   // preceding buckets full -> +t*NPB self-loops
  }
  if (t == 0){ bbase[NB] = E; offs[N] = E + N; }
}

// pack (src, local dst) into uint32: src<<9 | dl (N=100k < 2^17 -> fits).
__global__ void k_bscatter(const int* __restrict__ edge, int E, int NB,
                           int* __restrict__ bcur, unsigned* __restrict__ buf){
  __shared__ int lcnt[1024];
  __shared__ int lcur[1024];
  int t = threadIdx.x;
  int chunk = (E + gridDim.x - 1) / gridDim.x;
  int beg = blockIdx.x*chunk, end = min(E, beg + chunk);
  for (int i = t; i < NB; i += blockDim.x) lcnt[i] = 0;
  __syncthreads();
  for (int i = beg + t; i < end; i += blockDim.x)
    atomicAdd(&lcnt[edge[E + i] >> 9], 1);
  __syncthreads();
  for (int i = t; i < NB; i += blockDim.x){
    int c = lcnt[i];
    lcur[i] = c ? atomicAdd(&bcur[i], c) : 0;
  }
  __syncthreads();
  for (int i = beg + t; i < end; i += blockDim.x){
    int sN = edge[i], d = edge[E + i];
    int pos = atomicAdd(&lcur[d >> 9], 1);
    buf[pos] = ((unsigned)sN << 9) | (unsigned)(d & 511);
  }
}

__global__ void k_bbuild(const unsigned* __restrict__ buf, const int* __restrict__ bbase,
                         const int* __restrict__ sbase, int N,
                         int* __restrict__ offs, int* __restrict__ srcs){
  __shared__ int s[NPB];
  __shared__ int cur[NPB];
  int b = blockIdx.x, t = threadIdx.x;
  int base = b << 9;
  int nn = min(NPB, N - base);
  int sbeg = bbase[b], send = bbase[b+1];
  int sb = sbase[b];
  s[t] = (t < nn) ? 1 : 0;                 // self-loop seed
  __syncthreads();
  for (int i = sbeg + t; i < send; i += NPB)
    atomicAdd(&s[buf[i] & 511u], 1);
  __syncthreads();
  int c0 = s[t];
  __syncthreads();
  for (int d = 1; d < NPB; d <<= 1){
    int v = (t >= d) ? s[t-d] : 0;
    __syncthreads();
    s[t] += v;
    __syncthreads();
  }
  int start = s[t] - c0;
  if (t < nn){
    offs[base + t] = sb + start;
    srcs[sb + start] = base + t;           // self-loop
    cur[t] = start + 1;
  }
  __syncthreads();
  for (int i = sbeg + t; i < send; i += NPB){
    unsigned v = buf[i];
    int pos = atomicAdd(&cur[v & 511u], 1);
    srcs[sb + pos] = (int)(v >> 9);
  }
}

// ---- GAT node transform v2 (R8, working): W in VGPRs, x broadcast ------

template<int K, bool BF16IN>
__global__ void k_transform(const void* __restrict__ xin_,
                            const float* __restrict__ W,
                            const float* __restrict__ a_s,
                            const float* __restrict__ a_d,
                            bf* __restrict__ feat,
                            float* __restrict__ asrc, float* __restrict__ adst, int N){
  int t = threadIdx.x, lane = t & 63, wid = t >> 6;
  float wreg[K];
  #pragma unroll
  for (int k = 0; k < K; k++) wreg[k] = W[k*HC + lane];   // coalesced 256B per k
  float as_l = a_s[lane], ad_l = a_d[lane];
  int gw = blockIdx.x*(blockDim.x >> 6) + wid;
  int nw = gridDim.x*(blockDim.x >> 6);
  for (int n = gw; n < N; n += nw){
    float acc = 0.f;
    if (BF16IN){
      const bf* xr = (const bf*)xin_ + (size_t)n*K;
      #pragma unroll
      for (int k = 0; k < K; k += 8){
        uint4 d = *(const uint4*)(xr + k);                // same-addr broadcast
        acc = fmaf(__int_as_float((int)(d.x << 16)),         wreg[k+0], acc);
        acc = fmaf(__int_as_float((int)(d.x & 0xffff0000u)), wreg[k+1], acc);
        acc = fmaf(__int_as_float((int)(d.y << 16)),         wreg[k+2], acc);
        acc = fmaf(__int_as_float((int)(d.y & 0xffff0000u)), wreg[k+3], acc);
        acc = fmaf(__int_as_float((int)(d.z << 16)),         wreg[k+4], acc);
        acc = fmaf(__int_as_float((int)(d.z & 0xffff0000u)), wreg[k+5], acc);
        acc = fmaf(__int_as_float((int)(d.w << 16)),         wreg[k+6], acc);
        acc = fmaf(__int_as_float((int)(d.w & 0xffff0000u)), wreg[k+7], acc);
      }
    } else {
      const float* xr = (const float*)xin_ + (size_t)n*K;
      #pragma unroll
      for (int k = 0; k < K; k += 4){
        float4 xv = *(const float4*)(xr + k);             // same-addr broadcast
        acc = fmaf(xv.x, wreg[k+0], acc);
        acc = fmaf(xv.y, wreg[k+1], acc);
        acc = fmaf(xv.z, wreg[k+2], acc);
        acc = fmaf(xv.w, wreg[k+3], acc);
      }
    }
    feat[((size_t)n << 6) + lane] = __float2bfloat16(acc);
    float ps = acc*as_l, pd = acc*ad_l;
    #pragma unroll
    for (int d = 1; d < 16; d <<= 1){ ps += __shfl_xor(ps, d); pd += __shfl_xor(pd, d); }
    if ((lane & 15) == 0){
      asrc[n*4 + (lane>>4)] = ps;
      adst[n*4 + (lane>>4)] = pd;
    }
  }
}

// ---- softmax-aggregate v3 (R8, 111 us, REVERTED from v5) ---------------
// 2 edges/iter: each global_load_dword touches exactly 2 random 128-B
// segments per wave. R9's v5 (8 segments/instr) regressed 2-3x: WRITE_SIZE
// x4, VALUBusy 50->20% -- segment walk serializes inside one instruction.
// Keep <=2 random segments per VMEM instruction.

template<bool FINAL>
__global__ void k_aggregate(const int* __restrict__ offs, const int* __restrict__ srcs,
                            const bf* __restrict__ feat,
                            const float* __restrict__ asrc, const float* __restrict__ adst,
                            const float* __restrict__ bias,
                            bf* __restrict__ out,
                            const int* __restrict__ batch,
                            float* __restrict__ pooled, int N){
  __shared__ float2 lwh[4][4][66];         // [wave][head][edge slot(+pad)]
  int t = threadIdx.x, lane = t & 63, wid = t >> 6;
  int n = blockIdx.x*(blockDim.x >> 6) + wid;
  if (n >= N) return;
  int cl = lane & 31, half = lane >> 5, h2 = cl >> 3;
  const float4 adv = *(const float4*)(adst + (size_t)n*4);
  int beg = offs[n], end = offs[n+1];
  float2 acc = make_float2(0.f, 0.f);
  float den = 0.f;
  const float2* lp = &lwh[wid][h2][half];
  for (int j0 = beg; j0 < end; j0 += 64){
    int m = end - j0; if (m > 64) m = 64;
    // phase A: lane = edge (pad lanes write w=0, s=0)
    int sv = (lane < m) ? srcs[j0 + lane] : 0;
    float4 av = *(const float4*)(asrc + (size_t)sv*4);
    float z = (lane < m) ? 1.f : 0.f;
    float e0 = av.x + adv.x; e0 = (e0>0.f)?e0:0.2f*e0;
    float e1 = av.y + adv.y; e1 = (e1>0.f)?e1:0.2f*e1;
    float e2 = av.z + adv.z; e2 = (e2>0.f)?e2:0.2f*e2;
    float e3 = av.w + adv.w; e3 = (e3>0.f)?e3:0.2f*e3;
    float sb = __int_as_float(sv);
    lwh[wid][0][lane] = make_float2(z*__expf(e0), sb);
    lwh[wid][1][lane] = make_float2(z*__expf(e1), sb);
    lwh[wid][2][lane] = make_float2(z*__expf(e2), sb);
    lwh[wid][3][lane] = make_float2(z*__expf(e3), sb);
    // phase B: lane = (channel-pair, edge-half); 2 edges per iteration
    #pragma unroll 4
    for (int jj = 0; jj < m; jj += 2){
      float2 rec = lp[jj];                 // (w for my head, src bits)
      int s = __float_as_int(rec.y);
      unsigned d = ((const unsigned*)(feat + ((size_t)s << 6)))[cl];
      acc.x = fmaf(rec.x, __int_as_float((int)(d << 16)),         acc.x);
      acc.y = fmaf(rec.x, __int_as_float((int)(d & 0xffff0000u)), acc.y);
      den += rec.x;
    }
  }
  acc.x += __shfl_xor(acc.x, 32);
  acc.y += __shfl_xor(acc.y, 32);
  den   += __shfl_xor(den, 32);
  if (lane < 32){
    int c0 = cl << 1;
    float rx = acc.x/den + bias[c0];
    float ry = acc.y/den + bias[c0+1];
    rx = (rx>0.f)?rx:expm1f(rx);           // elu
    ry = (ry>0.f)?ry:expm1f(ry);
    if (FINAL){
      float* pg = pooled + (size_t)batch[n]*HC + c0;
      atomicAdd(pg, rx); atomicAdd(pg+1, ry);
    } else {
      __hip_bfloat162 p2;
      p2.x = __float2bfloat16(rx);
      p2.y = __float2bfloat16(ry);
      *(__hip_bfloat162*)(out + ((size_t)n << 6) + c0) = p2;
    }
  }
}

// ---- head: mean-pool already summed; MLPs. fp32 output -----------------

__global__ void k_final(const float* __restrict__ pooled, const int* __restrict__ gcnt,
                        const float* __restrict__ guid,
                        const float* __restrict__ Wg, const float* __restrict__ bg,
                        const float* __restrict__ Wu, const float* __restrict__ bu,
                        const float* __restrict__ Wo, const float* __restrict__ bo,
                        float* __restrict__ outp, int G){
  __shared__ float sWg[HC*16], sWo[16*7], sbg[16], sWu[16], sbu[16], sbo[7];
  int t = threadIdx.x;
  for (int i = t; i < HC*16; i += blockDim.x) sWg[i] = Wg[i];
  for (int i = t; i < 16*7;  i += blockDim.x) sWo[i] = Wo[i];
  if (t < 16){ sbg[t] = bg[t]; sWu[t] = Wu[t]; sbu[t] = bu[t]; }
  if (t < 7) sbo[t] = bo[t];
  __syncthreads();
  int g = blockIdx.x*blockDim.x + t;
  if (g >= G) return;
  float inv = 1.f / fmaxf((float)gcnt[g], 1.f);
  float v[16];
  #pragma unroll
  for (int j = 0; j < 16; j++) v[j] = sbg[j];
  for (int c = 0; c < HC; c++){
    float pc = pooled[g*HC + c] * inv;
    #pragma unroll
    for (int j = 0; j < 16; j++) v[j] = fmaf(pc, sWg[c*16 + j], v[j]);
  }
  float gd = guid[g];
  #pragma unroll
  for (int j = 0; j < 16; j++){
    float u = fmaf(gd, sWu[j], sbu[j]);
    v[j] += (u > 0.f) ? u : 0.f;
  }
  #pragma unroll
  for (int k = 0; k < 7; k++){
    float o = sbo[k];
    #pragma unroll
    for (int j = 0; j < 16; j++) o = fmaf(v[j], sWo[j*7 + k], o);
    outp[g*7 + k] = o;
  }
}

// ---- launch ------------------------------------------------------------

extern "C" void kernel_launch(void* const* d_in, const int* in_sizes, int n_in,
                              void* d_out, int out_size, void* d_ws, size_t ws_size,
                              hipStream_t stream){
  const float* x    = (const float*)d_in[0];
  const int*   edge = (const int*)d_in[1];
  const int*   batch= (const int*)d_in[2];
  const float* guid = (const float*)d_in[3];
  const float* W1   = (const float*)d_in[4];
  const float* as1  = (const float*)d_in[5];
  const float* ad1  = (const float*)d_in[6];
  const float* b1   = (const float*)d_in[7];
  const float* W2   = (const float*)d_in[8];
  const float* as2  = (const float*)d_in[9];
  const float* ad2  = (const float*)d_in[10];
  const float* b2   = (const float*)d_in[11];
  const float* Wg   = (const float*)d_in[12];
  const float* bg   = (const float*)d_in[13];
  const float* Wu   = (const float*)d_in[14];
  const float* bu   = (const float*)d_in[15];
  const float* Wo   = (const float*)d_in[16];
  const float* bo   = (const float*)d_in[17];

  const int N = in_sizes[0] / DIN;
  const int E = in_sizes[1] / 2;
  const int G = in_sizes[3];
  const int NB = (N + NPB - 1) >> 9;

  char* p = (char*)d_ws;
  auto alloc = [&](size_t nbytes)->void*{
    void* r = (void*)p;
    p += ((nbytes + 255) & ~(size_t)255);
    return r;
  };
  char*  zstart = p;                       // bc|gcnt|pooled zeroed together
  int*   bc     = (int*)  alloc(1024*4);
  int*   gcnt   = (int*)  alloc((size_t)G*4);
  float* pooled = (float*)alloc((size_t)G*HC*4);
  size_t zbytes = (size_t)(p - zstart);
  int*   bbase  = (int*)  alloc(1025*4);
  int*   bcur   = (int*)  alloc(1024*4);
  int*   sbase  = (int*)  alloc(1025*4);
  int*   offs   = (int*)  alloc((size_t)(N+1)*4);
  int*   srcs   = (int*)  alloc(((size_t)E + N)*4);
  bf*    featA  = (bf*)   alloc((size_t)N*HC*2);   // bf16 feature tables
  bf*    featB  = (bf*)   alloc((size_t)N*HC*2);
  float* asrc   = (float*)alloc((size_t)N*4*4);
  float* adst   = (float*)alloc((size_t)N*4*4);
  size_t featBytes = (size_t)(((char*)asrc) - ((char*)featA));
  unsigned* buf = ((size_t)E*4 <= featBytes) ? (unsigned*)featA
                                             : (unsigned*)alloc((size_t)E*4);
  (void)ws_size; (void)n_in; (void)out_size;

  hipMemsetAsync(zstart, 0, zbytes, stream);

  k_bhist   <<<256, 256, 0, stream>>>(edge, batch, E, N, NB, bc, gcnt);
  k_bscan   <<<1, 1024, 0, stream>>>(bc, NB, E, N, bbase, bcur, sbase, offs);
  k_bscatter<<<256, 256, 0, stream>>>(edge, E, NB, bcur, buf);
  k_bbuild  <<<NB, NPB, 0, stream>>>(buf, bbase, sbase, N, offs, srcs);

  const int tpb = 256;
  const int nb  = (N + 3) / 4;             // aggregate: 1 node per wave
  const int ntb = 1024;                    // transform: grid-stride
  k_transform<DIN, false><<<ntb, tpb, 0, stream>>>(x, W1, as1, ad1, featA, asrc, adst, N);
  k_aggregate<false><<<nb, tpb, 0, stream>>>(offs, srcs, featA, asrc, adst, b1, featB, batch, pooled, N);
  k_transform<HC, true><<<ntb, tpb, 0, stream>>>(featB, W2, as2, ad2, featA, asrc, adst, N);
  k_aggregate<true><<<nb, tpb, 0, stream>>>(offs, srcs, featA, asrc, adst, b2, nullptr, batch, pooled, N);

  k_final<<<(G+255)/256, 256, 0, stream>>>(pooled, gcnt, guid, Wg, bg, Wu, bu, Wo, bo,
                                           (float*)d_out, G);
}

// Round 11
// 436.210 us; speedup vs baseline: 1.6130x; 1.1110x over previous
//
#include <hip/hip_runtime.h>
#include <hip/hip_bf16.h>

#define DIN 32
#define HC  64   // H*C
#define NPB 512  // nodes per bucket (dst >> 9)

using bf = __hip_bfloat16;
static __device__ __forceinline__ float b2f(bf v){ return __bfloat162float(v); }

// ---- bucketed CSR build (R7/R10, working) ------------------------------

__global__ void k_bscan(const int* __restrict__ bc, int NB, int E, int N,
                        int* __restrict__ bbase, int* __restrict__ bcur,
                        int* __restrict__ sbase, int* __restrict__ offs){
  __shared__ int s[1024];
  int t = threadIdx.x;
  int mine = (t < NB) ? bc[t] : 0;
  s[t] = mine; __syncthreads();
  for (int d = 1; d < 1024; d <<= 1){
    int v = (t >= d) ? s[t-d] : 0;
    __syncthreads();
    s[t] += v;
    __syncthreads();
  }
  int excl = s[t] - mine;
  if (t < NB){
    bbase[t] = excl;
    bcur[t]  = excl;
    sbase[t] = excl + t*NPB;   // preceding buckets full -> +t*NPB self-loops
  }
  if (t == 0){ bbase[NB] = E; offs[N] = E + N; }
}

// pack (src, local dst) into uint32: src<<9 | dl (N=100k < 2^17 -> fits).
__global__ void k_bscatter(const int* __restrict__ edge, int E, int NB,
                           int* __restrict__ bcur, unsigned* __restrict__ buf){
  __shared__ int lcnt[1024];
  __shared__ int lcur[1024];
  int t = threadIdx.x;
  int chunk = (E + gridDim.x - 1) / gridDim.x;
  int beg = blockIdx.x*chunk, end = min(E, beg + chunk);
  for (int i = t; i < NB; i += blockDim.x) lcnt[i] = 0;
  __syncthreads();
  for (int i = beg + t; i < end; i += blockDim.x)
    atomicAdd(&lcnt[edge[E + i] >> 9], 1);
  __syncthreads();
  for (int i = t; i < NB; i += blockDim.x){
    int c = lcnt[i];
    lcur[i] = c ? atomicAdd(&bcur[i], c) : 0;
  }
  __syncthreads();
  for (int i = beg + t; i < end; i += blockDim.x){
    int sN = edge[i], d = edge[E + i];
    int pos = atomicAdd(&lcur[d >> 9], 1);
    buf[pos] = ((unsigned)sN << 9) | (unsigned)(d & 511);
  }
}

__global__ void k_bbuild(const unsigned* __restrict__ buf, const int* __restrict__ bbase,
                         const int* __restrict__ sbase, int N,
                         int* __restrict__ offs, int* __restrict__ srcs){
  __shared__ int s[NPB];
  __shared__ int cur[NPB];
  int b = blockIdx.x, t = threadIdx.x;
  int base = b << 9;
  int nn = min(NPB, N - base);
  int sbeg = bbase[b], send = bbase[b+1];
  int sb = sbase[b];
  s[t] = (t < nn) ? 1 : 0;                 // self-loop seed
  __syncthreads();
  for (int i = sbeg + t; i < send; i += NPB)
    atomicAdd(&s[buf[i] & 511u], 1);
  __syncthreads();
  int c0 = s[t];
  __syncthreads();
  for (int d = 1; d < NPB; d <<= 1){
    int v = (t >= d) ? s[t-d] : 0;
    __syncthreads();
    s[t] += v;
    __syncthreads();
  }
  int start = s[t] - c0;
  if (t < nn){
    offs[base + t] = sb + start;
    srcs[sb + start] = base + t;           // self-loop
    cur[t] = start + 1;
  }
  __syncthreads();
  for (int i = sbeg + t; i < send; i += NPB){
    unsigned v = buf[i];
    int pos = atomicAdd(&cur[v & 511u], 1);
    srcs[sb + pos] = (int)(v >> 9);
  }
}

// ---- fused: transform layer-1 (blocks < TB)  ||  bucket+graph hist -----
// (independent work: tf reads x -> featB/asrc/adst; hist reads edge/batch
//  -> bc/gcnt. Saves a dispatch and overlaps the two.)

template<int K, bool BF16IN>
__global__ void k_tf_hist(const void* __restrict__ xin_,
                          const float* __restrict__ W,
                          const float* __restrict__ a_s,
                          const float* __restrict__ a_d,
                          bf* __restrict__ feat,
                          float* __restrict__ asrc, float* __restrict__ adst, int N,
                          const int* __restrict__ edge, const int* __restrict__ batch,
                          int E, int NB, int* __restrict__ bc, int* __restrict__ gcnt,
                          int TB){
  __shared__ int lh[1024];
  int t = threadIdx.x;
  if ((int)blockIdx.x >= TB){                // ---- hist part ----
    for (int i = t; i < NB; i += blockDim.x) lh[i] = 0;
    __syncthreads();
    int hb = blockIdx.x - TB;
    int HB = gridDim.x - TB;
    int M = max(E, N);
    int stride = HB*blockDim.x;
    for (int i = hb*blockDim.x + t; i < M; i += stride){
      if (i < E) atomicAdd(&lh[edge[E + i] >> 9], 1);
      if (i < N) atomicAdd(&gcnt[batch[i]], 1); // sorted batch -> coalesced
    }
    __syncthreads();
    for (int i = t; i < NB; i += blockDim.x){ int c = lh[i]; if (c) atomicAdd(&bc[i], c); }
    return;
  }
  // ---- transform part (R8 v2: W column in VGPRs, x same-addr broadcast)
  int lane = t & 63, wid = t >> 6;
  float wreg[K];
  #pragma unroll
  for (int k = 0; k < K; k++) wreg[k] = W[k*HC + lane];
  float as_l = a_s[lane], ad_l = a_d[lane];
  int gw = blockIdx.x*4 + wid;
  int nw = TB*4;
  for (int n = gw; n < N; n += nw){
    float acc = 0.f;
    if (BF16IN){
      const bf* xr = (const bf*)xin_ + (size_t)n*K;
      #pragma unroll
      for (int k = 0; k < K; k += 8){
        uint4 d = *(const uint4*)(xr + k);
        acc = fmaf(__int_as_float((int)(d.x << 16)),         wreg[k+0], acc);
        acc = fmaf(__int_as_float((int)(d.x & 0xffff0000u)), wreg[k+1], acc);
        acc = fmaf(__int_as_float((int)(d.y << 16)),         wreg[k+2], acc);
        acc = fmaf(__int_as_float((int)(d.y & 0xffff0000u)), wreg[k+3], acc);
        acc = fmaf(__int_as_float((int)(d.z << 16)),         wreg[k+4], acc);
        acc = fmaf(__int_as_float((int)(d.z & 0xffff0000u)), wreg[k+5], acc);
        acc = fmaf(__int_as_float((int)(d.w << 16)),         wreg[k+6], acc);
        acc = fmaf(__int_as_float((int)(d.w & 0xffff0000u)), wreg[k+7], acc);
      }
    } else {
      const float* xr = (const float*)xin_ + (size_t)n*K;
      #pragma unroll
      for (int k = 0; k < K; k += 4){
        float4 xv = *(const float4*)(xr + k);
        acc = fmaf(xv.x, wreg[k+0], acc);
        acc = fmaf(xv.y, wreg[k+1], acc);
        acc = fmaf(xv.z, wreg[k+2], acc);
        acc = fmaf(xv.w, wreg[k+3], acc);
      }
    }
    feat[((size_t)n << 6) + lane] = __float2bfloat16(acc);
    float ps = acc*as_l, pd = acc*ad_l;
    #pragma unroll
    for (int d = 1; d < 16; d <<= 1){ ps += __shfl_xor(ps, d); pd += __shfl_xor(pd, d); }
    if ((lane & 15) == 0){
      asrc[n*4 + (lane>>4)] = ps;
      adst[n*4 + (lane>>4)] = pd;
    }
  }
}

// standalone transform for layer 2
template<int K, bool BF16IN>
__global__ void k_transform(const void* __restrict__ xin_,
                            const float* __restrict__ W,
                            const float* __restrict__ a_s,
                            const float* __restrict__ a_d,
                            bf* __restrict__ feat,
                            float* __restrict__ asrc, float* __restrict__ adst, int N){
  int t = threadIdx.x, lane = t & 63, wid = t >> 6;
  float wreg[K];
  #pragma unroll
  for (int k = 0; k < K; k++) wreg[k] = W[k*HC + lane];
  float as_l = a_s[lane], ad_l = a_d[lane];
  int gw = blockIdx.x*4 + wid;
  int nw = gridDim.x*4;
  for (int n = gw; n < N; n += nw){
    float acc = 0.f;
    if (BF16IN){
      const bf* xr = (const bf*)xin_ + (size_t)n*K;
      #pragma unroll
      for (int k = 0; k < K; k += 8){
        uint4 d = *(const uint4*)(xr + k);
        acc = fmaf(__int_as_float((int)(d.x << 16)),         wreg[k+0], acc);
        acc = fmaf(__int_as_float((int)(d.x & 0xffff0000u)), wreg[k+1], acc);
        acc = fmaf(__int_as_float((int)(d.y << 16)),         wreg[k+2], acc);
        acc = fmaf(__int_as_float((int)(d.y & 0xffff0000u)), wreg[k+3], acc);
        acc = fmaf(__int_as_float((int)(d.z << 16)),         wreg[k+4], acc);
        acc = fmaf(__int_as_float((int)(d.z & 0xffff0000u)), wreg[k+5], acc);
        acc = fmaf(__int_as_float((int)(d.w << 16)),         wreg[k+6], acc);
        acc = fmaf(__int_as_float((int)(d.w & 0xffff0000u)), wreg[k+7], acc);
      }
    } else {
      const float* xr = (const float*)xin_ + (size_t)n*K;
      #pragma unroll
      for (int k = 0; k < K; k += 4){
        float4 xv = *(const float4*)(xr + k);
        acc = fmaf(xv.x, wreg[k+0], acc);
        acc = fmaf(xv.y, wreg[k+1], acc);
        acc = fmaf(xv.z, wreg[k+2], acc);
        acc = fmaf(xv.w, wreg[k+3], acc);
      }
    }
    feat[((size_t)n << 6) + lane] = __float2bfloat16(acc);
    float ps = acc*as_l, pd = acc*ad_l;
    #pragma unroll
    for (int d = 1; d < 16; d <<= 1){ ps += __shfl_xor(ps, d); pd += __shfl_xor(pd, d); }
    if ((lane & 15) == 0){
      asrc[n*4 + (lane>>4)] = ps;
      adst[n*4 + (lane>>4)] = pd;
    }
  }
}

// ---- softmax-aggregate v6 ----------------------------------------------
// v3 memory pattern (2 random 128-B segments per VMEM instr — R9 showed
// wider is catastrophic). New: (a) LDS carries (w, src*32) so feat index
// is one v_add on a uniform base; (b) epilogue spreads channels to all 64
// lanes -> 2 B/lane stores (WRITE_SIZE scales with lane store width:
// 2B->25MB, 4B->50MB, 16B->200MB measured R5/R10/R9); (c) FINAL pools via
// block-level LDS combine: batch sorted -> 4 nodes/block usually one graph
// -> 1 atomic set per block (4x fewer).

template<bool FINAL>
__global__ void k_aggregate(const int* __restrict__ offs, const int* __restrict__ srcs,
                            const bf* __restrict__ feat,
                            const float* __restrict__ asrc, const float* __restrict__ adst,
                            const float* __restrict__ bias,
                            bf* __restrict__ out,
                            const int* __restrict__ batch,
                            float* __restrict__ pooled, int N){
  __shared__ float2 lwh[4][4][66];         // [wave][head][edge slot(+pad)]
  __shared__ float red[4][HC];             // FINAL block combine
  int t = threadIdx.x, lane = t & 63, wid = t >> 6;
  int n = blockIdx.x*4 + wid;
  bool active = (n < N);
  if (!FINAL && !active) return;
  int ns = active ? n : (N-1);             // safe index for inactive tail waves
  int cl = lane & 31, half = lane >> 5, h2 = cl >> 3;
  const float4 adv = *(const float4*)(adst + (size_t)ns*4);
  int beg = offs[ns], end = offs[ns+1];
  float2 acc = make_float2(0.f, 0.f);
  float den = 0.f;
  const float2* lp = &lwh[wid][h2][half];
  const unsigned* featU = (const unsigned*)feat;   // uniform base + voffset
  for (int j0 = beg; j0 < end; j0 += 64){
    int m = end - j0; if (m > 64) m = 64;
    // phase A: lane = edge (pad lanes write w=0 -> no contribution)
    int sv = (lane < m) ? srcs[j0 + lane] : 0;
    float4 av = *(const float4*)(asrc + (size_t)sv*4);
    float z = (lane < m) ? 1.f : 0.f;
    float e0 = av.x + adv.x; e0 = (e0>0.f)?e0:0.2f*e0;
    float e1 = av.y + adv.y; e1 = (e1>0.f)?e1:0.2f*e1;
    float e2 = av.z + adv.z; e2 = (e2>0.f)?e2:0.2f*e2;
    float e3 = av.w + adv.w; e3 = (e3>0.f)?e3:0.2f*e3;
    float ob = __int_as_float(sv << 5);    // dword row offset (row = 32 dwords)
    lwh[wid][0][lane] = make_float2(z*__expf(e0), ob);
    lwh[wid][1][lane] = make_float2(z*__expf(e1), ob);
    lwh[wid][2][lane] = make_float2(z*__expf(e2), ob);
    lwh[wid][3][lane] = make_float2(z*__expf(e3), ob);
    // phase B: lane = (channel-pair, edge-half); 2 edges per iteration
    #pragma unroll 8
    for (int jj = 0; jj < m; jj += 2){
      float2 rec = lp[jj];                 // (w for my head, row offset bits)
      unsigned idx = (unsigned)__float_as_int(rec.y) | (unsigned)cl;
      unsigned d = featU[idx];
      acc.x = fmaf(rec.x, __int_as_float((int)(d << 16)),         acc.x);
      acc.y = fmaf(rec.x, __int_as_float((int)(d & 0xffff0000u)), acc.y);
      den += rec.x;
    }
  }
  acc.x += __shfl_xor(acc.x, 32);
  acc.y += __shfl_xor(acc.y, 32);
  den   += __shfl_xor(den, 32);            // all 64 lanes now hold totals
  // spread: channel c = lane; source lane = lane>>1, pick x/y by parity
  float vx = __shfl(acc.x, lane >> 1);
  float vy = __shfl(acc.y, lane >> 1);
  float r = ((lane & 1) ? vy : vx)/den + bias[lane];
  r = (r > 0.f) ? r : expm1f(r);           // elu
  if (FINAL){
    red[wid][lane] = active ? r : 0.f;
    __syncthreads();
    if (wid == 0){
      int n0 = blockIdx.x*4;
      int g0 = batch[min(n0, N-1)];
      int g3 = batch[min(n0+3, N-1)];
      float s4 = red[0][lane] + red[1][lane] + red[2][lane] + red[3][lane];
      if (g0 == g3){                       // fast path (~96% of blocks)
        atomicAdd(&pooled[(size_t)g0*HC + lane], s4);
      } else {
        for (int w2 = 0; w2 < 4; w2++){
          int nw = n0 + w2;
          if (nw < N) atomicAdd(&pooled[(size_t)batch[nw]*HC + lane], red[w2][lane]);
        }
      }
    }
  } else {
    out[((size_t)n << 6) + lane] = __float2bfloat16(r);   // 2 B/lane store
  }
}

// ---- head: mean-pool already summed; MLPs. fp32 output -----------------

__global__ void k_final(const float* __restrict__ pooled, const int* __restrict__ gcnt,
                        const float* __restrict__ guid,
                        const float* __restrict__ Wg, const float* __restrict__ bg,
                        const float* __restrict__ Wu, const float* __restrict__ bu,
                        const float* __restrict__ Wo, const float* __restrict__ bo,
                        float* __restrict__ outp, int G){
  __shared__ float sWg[HC*16], sWo[16*7], sbg[16], sWu[16], sbu[16], sbo[7];
  int t = threadIdx.x;
  for (int i = t; i < HC*16; i += blockDim.x) sWg[i] = Wg[i];
  for (int i = t; i < 16*7;  i += blockDim.x) sWo[i] = Wo[i];
  if (t < 16){ sbg[t] = bg[t]; sWu[t] = Wu[t]; sbu[t] = bu[t]; }
  if (t < 7) sbo[t] = bo[t];
  __syncthreads();
  int g = blockIdx.x*blockDim.x + t;
  if (g >= G) return;
  float inv = 1.f / fmaxf((float)gcnt[g], 1.f);
  float v[16];
  #pragma unroll
  for (int j = 0; j < 16; j++) v[j] = sbg[j];
  for (int c = 0; c < HC; c++){
    float pc = pooled[g*HC + c] * inv;
    #pragma unroll
    for (int j = 0; j < 16; j++) v[j] = fmaf(pc, sWg[c*16 + j], v[j]);
  }
  float gd = guid[g];
  #pragma unroll
  for (int j = 0; j < 16; j++){
    float u = fmaf(gd, sWu[j], sbu[j]);
    v[j] += (u > 0.f) ? u : 0.f;
  }
  #pragma unroll
  for (int k = 0; k < 7; k++){
    float o = sbo[k];
    #pragma unroll
    for (int j = 0; j < 16; j++) o = fmaf(v[j], sWo[j*7 + k], o);
    outp[g*7 + k] = o;
  }
}

// ---- launch ------------------------------------------------------------

extern "C" void kernel_launch(void* const* d_in, const int* in_sizes, int n_in,
                              void* d_out, int out_size, void* d_ws, size_t ws_size,
                              hipStream_t stream){
  const float* x    = (const float*)d_in[0];
  const int*   edge = (const int*)d_in[1];
  const int*   batch= (const int*)d_in[2];
  const float* guid = (const float*)d_in[3];
  const float* W1   = (const float*)d_in[4];
  const float* as1  = (const float*)d_in[5];
  const float* ad1  = (const float*)d_in[6];
  const float* b1   = (const float*)d_in[7];
  const float* W2   = (const float*)d_in[8];
  const float* as2  = (const float*)d_in[9];
  const float* ad2  = (const float*)d_in[10];
  const float* b2   = (const float*)d_in[11];
  const float* Wg   = (const float*)d_in[12];
  const float* bg   = (const float*)d_in[13];
  const float* Wu   = (const float*)d_in[14];
  const float* bu   = (const float*)d_in[15];
  const float* Wo   = (const float*)d_in[16];
  const float* bo   = (const float*)d_in[17];

  const int N = in_sizes[0] / DIN;
  const int E = in_sizes[1] / 2;
  const int G = in_sizes[3];
  const int NB = (N + NPB - 1) >> 9;

  char* p = (char*)d_ws;
  auto alloc = [&](size_t nbytes)->void*{
    void* r = (void*)p;
    p += ((nbytes + 255) & ~(size_t)255);
    return r;
  };
  char*  zstart = p;                       // bc|gcnt|pooled zeroed together
  int*   bc     = (int*)  alloc(1024*4);
  int*   gcnt   = (int*)  alloc((size_t)G*4);
  float* pooled = (float*)alloc((size_t)G*HC*4);
  size_t zbytes = (size_t)(p - zstart);
  int*   bbase  = (int*)  alloc(1025*4);
  int*   bcur   = (int*)  alloc(1024*4);
  int*   sbase  = (int*)  alloc(1025*4);
  int*   offs   = (int*)  alloc((size_t)(N+1)*4);
  int*   srcs   = (int*)  alloc(((size_t)E + N)*4);
  size_t featASz = (size_t)N*HC*2;
  if ((size_t)E*4 > featASz) featASz = (size_t)E*4;   // featA doubles as buf
  bf*    featA  = (bf*)   alloc(featASz);
  bf*    featB  = (bf*)   alloc((size_t)N*HC*2);
  float* asrc   = (float*)alloc((size_t)N*4*4);
  float* adst   = (float*)alloc((size_t)N*4*4);
  unsigned* buf = (unsigned*)featA;        // dead before aggregate1 writes featA
  (void)ws_size; (void)n_in; (void)out_size;

  hipMemsetAsync(zstart, 0, zbytes, stream);

  const int tpb = 256;
  const int TB  = 1024;                    // transform blocks in fused kernel
  // tf1: x -> featB  ||  hist -> bc,gcnt
  k_tf_hist<DIN, false><<<TB + 256, tpb, 0, stream>>>(
      x, W1, as1, ad1, featB, asrc, adst, N, edge, batch, E, NB, bc, gcnt, TB);
  k_bscan   <<<1, 1024, 0, stream>>>(bc, NB, E, N, bbase, bcur, sbase, offs);
  k_bscatter<<<256, 256, 0, stream>>>(edge, E, NB, bcur, buf);
  k_bbuild  <<<NB, NPB, 0, stream>>>(buf, bbase, sbase, N, offs, srcs);

  const int nb = (N + 3) / 4;              // aggregate: 1 node per wave
  // layer 1: aggregate featB -> featA (h1; overwrites dead buf)
  k_aggregate<false><<<nb, tpb, 0, stream>>>(offs, srcs, featB, asrc, adst, b1, featA, batch, pooled, N);
  // layer 2: transform featA -> featB ; aggregate featB -> pooled
  k_transform<HC, true><<<TB, tpb, 0, stream>>>(featA, W2, as2, ad2, featB, asrc, adst, N);
  k_aggregate<true><<<nb, tpb, 0, stream>>>(offs, srcs, featB, asrc, adst, b2, nullptr, batch, pooled, N);

  k_final<<<(G+255)/256, 256, 0, stream>>>(pooled, gcnt, guid, Wg, bg, Wu, bu, Wo, bo,
                                           (float*)d_out, G);
}

// Round 12
// 424.543 us; speedup vs baseline: 1.6574x; 1.0275x over previous
//
#include <hip/hip_runtime.h>
#include <hip/hip_bf16.h>

#define DIN 32
#define HC  64    // H*C
#define NPB 512   // nodes per bucket (dst >> 9)
#define CAP 20480 // fixed bucket capacity: E/NB=16384 expected, sigma~127 -> 32 sigma

using bf = __hip_bfloat16;
static __device__ __forceinline__ float b2f(bf v){ return __bfloat162float(v); }

// ---- bucketed CSR build, v2: no global pre-histogram -------------------
// R11 evidence: k_bhist duplicated bscatter's per-block LDS hist (85 us
// fused). Fixed-capacity bucket slots remove the need for global bases:
// bcur[b] (memset-0) counts fills; write pos = b*CAP + old.

__global__ void k_bscatter(const int* __restrict__ edge, int E, int NB,
                           int* __restrict__ bcur, unsigned* __restrict__ buf){
  __shared__ int lcnt[1024];
  __shared__ int lcur[1024];
  int t = threadIdx.x;
  int chunk = (E + gridDim.x - 1) / gridDim.x;
  int beg = blockIdx.x*chunk, end = min(E, beg + chunk);
  for (int i = t; i < NB; i += blockDim.x) lcnt[i] = 0;
  __syncthreads();
  for (int i = beg + t; i < end; i += blockDim.x)
    atomicAdd(&lcnt[edge[E + i] >> 9], 1);
  __syncthreads();
  for (int i = t; i < NB; i += blockDim.x){
    int c = lcnt[i];
    lcur[i] = i*CAP + (c ? atomicAdd(&bcur[i], c) : 0);
  }
  __syncthreads();
  for (int i = beg + t; i < end; i += blockDim.x){
    int sN = edge[i], d = edge[E + i];
    int pos = atomicAdd(&lcur[d >> 9], 1);
    buf[pos] = ((unsigned)sN << 9) | (unsigned)(d & 511);
  }
}

// one block: exclusive scan of bucket fills -> srcs bases; totals.
__global__ void k_bscan(const int* __restrict__ bcur, int NB, int E, int N,
                        int* __restrict__ sbase, int* __restrict__ offs){
  __shared__ int s[1024];
  int t = threadIdx.x;
  int mine = (t < NB) ? min(bcur[t], CAP) : 0;
  s[t] = mine; __syncthreads();
  for (int d = 1; d < 1024; d <<= 1){
    int v = (t >= d) ? s[t-d] : 0;
    __syncthreads();
    s[t] += v;
    __syncthreads();
  }
  if (t < NB) sbase[t] = (s[t] - mine) + t*NPB;  // + self-loops of prior buckets
  if (t == 0) offs[N] = E + N;
}

// one block (512 thr) per bucket: local CSR in LDS; self-loop at slot 0.
// Tail: per-graph node counts (batch sorted -> few distinct graphs/block).
__global__ void k_bbuild(const unsigned* __restrict__ buf, const int* __restrict__ bcur,
                         const int* __restrict__ sbase, const int* __restrict__ batch,
                         int N, int* __restrict__ offs, int* __restrict__ srcs,
                         int* __restrict__ gcnt){
  __shared__ int s[NPB];
  __shared__ int cur[NPB];
  int b = blockIdx.x, t = threadIdx.x;
  int base = b << 9;
  int nn = min(NPB, N - base);
  int sbeg = b*CAP;
  int send = sbeg + min(bcur[b], CAP);
  int sb = sbase[b];
  s[t] = (t < nn) ? 1 : 0;                 // self-loop seed
  __syncthreads();
  for (int i = sbeg + t; i < send; i += NPB)
    atomicAdd(&s[buf[i] & 511u], 1);
  __syncthreads();
  int c0 = s[t];
  __syncthreads();
  for (int d = 1; d < NPB; d <<= 1){
    int v = (t >= d) ? s[t-d] : 0;
    __syncthreads();
    s[t] += v;
    __syncthreads();
  }
  int start = s[t] - c0;
  if (t < nn){
    offs[base + t] = sb + start;
    srcs[sb + start] = base + t;           // self-loop
    cur[t] = start + 1;
    atomicAdd(&gcnt[batch[base + t]], 1);  // graph node count
  }
  __syncthreads();
  for (int i = sbeg + t; i < send; i += NPB){
    unsigned v = buf[i];
    int pos = atomicAdd(&cur[v & 511u], 1);
    srcs[sb + pos] = (int)(v >> 9);
  }
}

// ---- GAT node transform (R8 v2, standalone): W in VGPRs, x broadcast ---

template<int K, bool BF16IN>
__global__ void k_transform(const void* __restrict__ xin_,
                            const float* __restrict__ W,
                            const float* __restrict__ a_s,
                            const float* __restrict__ a_d,
                            bf* __restrict__ feat,
                            float* __restrict__ asrc, float* __restrict__ adst, int N){
  int t = threadIdx.x, lane = t & 63, wid = t >> 6;
  float wreg[K];
  #pragma unroll
  for (int k = 0; k < K; k++) wreg[k] = W[k*HC + lane];   // coalesced 256B per k
  float as_l = a_s[lane], ad_l = a_d[lane];
  int gw = blockIdx.x*4 + wid;
  int nw = gridDim.x*4;
  for (int n = gw; n < N; n += nw){
    float acc = 0.f;
    if (BF16IN){
      const bf* xr = (const bf*)xin_ + (size_t)n*K;
      #pragma unroll
      for (int k = 0; k < K; k += 8){
        uint4 d = *(const uint4*)(xr + k);                // same-addr broadcast
        acc = fmaf(__int_as_float((int)(d.x << 16)),         wreg[k+0], acc);
        acc = fmaf(__int_as_float((int)(d.x & 0xffff0000u)), wreg[k+1], acc);
        acc = fmaf(__int_as_float((int)(d.y << 16)),         wreg[k+2], acc);
        acc = fmaf(__int_as_float((int)(d.y & 0xffff0000u)), wreg[k+3], acc);
        acc = fmaf(__int_as_float((int)(d.z << 16)),         wreg[k+4], acc);
        acc = fmaf(__int_as_float((int)(d.z & 0xffff0000u)), wreg[k+5], acc);
        acc = fmaf(__int_as_float((int)(d.w << 16)),         wreg[k+6], acc);
        acc = fmaf(__int_as_float((int)(d.w & 0xffff0000u)), wreg[k+7], acc);
      }
    } else {
      const float* xr = (const float*)xin_ + (size_t)n*K;
      #pragma unroll
      for (int k = 0; k < K; k += 4){
        float4 xv = *(const float4*)(xr + k);             // same-addr broadcast
        acc = fmaf(xv.x, wreg[k+0], acc);
        acc = fmaf(xv.y, wreg[k+1], acc);
        acc = fmaf(xv.z, wreg[k+2], acc);
        acc = fmaf(xv.w, wreg[k+3], acc);
      }
    }
    feat[((size_t)n << 6) + lane] = __float2bfloat16(acc);
    float ps = acc*as_l, pd = acc*ad_l;
    #pragma unroll
    for (int d = 1; d < 16; d <<= 1){ ps += __shfl_xor(ps, d); pd += __shfl_xor(pd, d); }
    if ((lane & 15) == 0){
      asrc[n*4 + (lane>>4)] = ps;
      adst[n*4 + (lane>>4)] = pd;
    }
  }
}

// ---- softmax-aggregate v6 (R11, working) -------------------------------
// 2 random 128-B segments per VMEM instr (R9: wider regressed 2-3x).
// 2 B/lane epilogue stores (WRITE scales with lane store width: 2B->25MB,
// 4B->50MB, 16B->200MB measured). FINAL pools via block LDS combine.

template<bool FINAL>
__global__ void k_aggregate(const int* __restrict__ offs, const int* __restrict__ srcs,
                            const bf* __restrict__ feat,
                            const float* __restrict__ asrc, const float* __restrict__ adst,
                            const float* __restrict__ bias,
                            bf* __restrict__ out,
                            const int* __restrict__ batch,
                            float* __restrict__ pooled, int N){
  __shared__ float2 lwh[4][4][66];         // [wave][head][edge slot(+pad)]
  __shared__ float red[4][HC];             // FINAL block combine
  int t = threadIdx.x, lane = t & 63, wid = t >> 6;
  int n = blockIdx.x*4 + wid;
  bool active = (n < N);
  if (!FINAL && !active) return;
  int ns = active ? n : (N-1);             // safe index for inactive tail waves
  int cl = lane & 31, half = lane >> 5, h2 = cl >> 3;
  const float4 adv = *(const float4*)(adst + (size_t)ns*4);
  int beg = offs[ns], end = offs[ns+1];
  float2 acc = make_float2(0.f, 0.f);
  float den = 0.f;
  const float2* lp = &lwh[wid][h2][half];
  const unsigned* featU = (const unsigned*)feat;   // uniform base + voffset
  for (int j0 = beg; j0 < end; j0 += 64){
    int m = end - j0; if (m > 64) m = 64;
    // phase A: lane = edge (pad lanes write w=0 -> no contribution)
    int sv = (lane < m) ? srcs[j0 + lane] : 0;
    float4 av = *(const float4*)(asrc + (size_t)sv*4);
    float z = (lane < m) ? 1.f : 0.f;
    float e0 = av.x + adv.x; e0 = (e0>0.f)?e0:0.2f*e0;
    float e1 = av.y + adv.y; e1 = (e1>0.f)?e1:0.2f*e1;
    float e2 = av.z + adv.z; e2 = (e2>0.f)?e2:0.2f*e2;
    float e3 = av.w + adv.w; e3 = (e3>0.f)?e3:0.2f*e3;
    float ob = __int_as_float(sv << 5);    // dword row offset (row = 32 dwords)
    lwh[wid][0][lane] = make_float2(z*__expf(e0), ob);
    lwh[wid][1][lane] = make_float2(z*__expf(e1), ob);
    lwh[wid][2][lane] = make_float2(z*__expf(e2), ob);
    lwh[wid][3][lane] = make_float2(z*__expf(e3), ob);
    // phase B: lane = (channel-pair, edge-half); 2 edges per iteration
    #pragma unroll 8
    for (int jj = 0; jj < m; jj += 2){
      float2 rec = lp[jj];                 // (w for my head, row offset bits)
      unsigned idx = (unsigned)__float_as_int(rec.y) | (unsigned)cl;
      unsigned d = featU[idx];
      acc.x = fmaf(rec.x, __int_as_float((int)(d << 16)),         acc.x);
      acc.y = fmaf(rec.x, __int_as_float((int)(d & 0xffff0000u)), acc.y);
      den += rec.x;
    }
  }
  acc.x += __shfl_xor(acc.x, 32);
  acc.y += __shfl_xor(acc.y, 32);
  den   += __shfl_xor(den, 32);            // all 64 lanes now hold totals
  // spread: channel c = lane; source lane = lane>>1, pick x/y by parity
  float vx = __shfl(acc.x, lane >> 1);
  float vy = __shfl(acc.y, lane >> 1);
  float r = ((lane & 1) ? vy : vx)/den + bias[lane];
  r = (r > 0.f) ? r : expm1f(r);           // elu
  if (FINAL){
    red[wid][lane] = active ? r : 0.f;
    __syncthreads();
    if (wid == 0){
      int n0 = blockIdx.x*4;
      int g0 = batch[min(n0, N-1)];
      int g3 = batch[min(n0+3, N-1)];
      float s4 = red[0][lane] + red[1][lane] + red[2][lane] + red[3][lane];
      if (g0 == g3){                       // fast path (~96% of blocks)
        atomicAdd(&pooled[(size_t)g0*HC + lane], s4);
      } else {
        for (int w2 = 0; w2 < 4; w2++){
          int nw = n0 + w2;
          if (nw < N) atomicAdd(&pooled[(size_t)batch[nw]*HC + lane], red[w2][lane]);
        }
      }
    }
  } else {
    out[((size_t)n << 6) + lane] = __float2bfloat16(r);   // 2 B/lane store
  }
}

// ---- head: mean-pool already summed; MLPs. fp32 output -----------------

__global__ void k_final(const float* __restrict__ pooled, const int* __restrict__ gcnt,
                        const float* __restrict__ guid,
                        const float* __restrict__ Wg, const float* __restrict__ bg,
                        const float* __restrict__ Wu, const float* __restrict__ bu,
                        const float* __restrict__ Wo, const float* __restrict__ bo,
                        float* __restrict__ outp, int G){
  __shared__ float sWg[HC*16], sWo[16*7], sbg[16], sWu[16], sbu[16], sbo[7];
  int t = threadIdx.x;
  for (int i = t; i < HC*16; i += blockDim.x) sWg[i] = Wg[i];
  for (int i = t; i < 16*7;  i += blockDim.x) sWo[i] = Wo[i];
  if (t < 16){ sbg[t] = bg[t]; sWu[t] = Wu[t]; sbu[t] = bu[t]; }
  if (t < 7) sbo[t] = bo[t];
  __syncthreads();
  int g = blockIdx.x*blockDim.x + t;
  if (g >= G) return;
  float inv = 1.f / fmaxf((float)gcnt[g], 1.f);
  float v[16];
  #pragma unroll
  for (int j = 0; j < 16; j++) v[j] = sbg[j];
  for (int c = 0; c < HC; c++){
    float pc = pooled[g*HC + c] * inv;
    #pragma unroll
    for (int j = 0; j < 16; j++) v[j] = fmaf(pc, sWg[c*16 + j], v[j]);
  }
  float gd = guid[g];
  #pragma unroll
  for (int j = 0; j < 16; j++){
    float u = fmaf(gd, sWu[j], sbu[j]);
    v[j] += (u > 0.f) ? u : 0.f;
  }
  #pragma unroll
  for (int k = 0; k < 7; k++){
    float o = sbo[k];
    #pragma unroll
    for (int j = 0; j < 16; j++) o = fmaf(v[j], sWo[j*7 + k], o);
    outp[g*7 + k] = o;
  }
}

// ---- launch ------------------------------------------------------------

extern "C" void kernel_launch(void* const* d_in, const int* in_sizes, int n_in,
                              void* d_out, int out_size, void* d_ws, size_t ws_size,
                              hipStream_t stream){
  const float* x    = (const float*)d_in[0];
  const int*   edge = (const int*)d_in[1];
  const int*   batch= (const int*)d_in[2];
  const float* guid = (const float*)d_in[3];
  const float* W1   = (const float*)d_in[4];
  const float* as1  = (const float*)d_in[5];
  const float* ad1  = (const float*)d_in[6];
  const float* b1   = (const float*)d_in[7];
  const float* W2   = (const float*)d_in[8];
  const float* as2  = (const float*)d_in[9];
  const float* ad2  = (const float*)d_in[10];
  const float* b2   = (const float*)d_in[11];
  const float* Wg   = (const float*)d_in[12];
  const float* bg   = (const float*)d_in[13];
  const float* Wu   = (const float*)d_in[14];
  const float* bu   = (const float*)d_in[15];
  const float* Wo   = (const float*)d_in[16];
  const float* bo   = (const float*)d_in[17];

  const int N = in_sizes[0] / DIN;
  const int E = in_sizes[1] / 2;
  const int G = in_sizes[3];
  const int NB = (N + NPB - 1) >> 9;

  char* p = (char*)d_ws;
  auto alloc = [&](size_t nbytes)->void*{
    void* r = (void*)p;
    p += ((nbytes + 255) & ~(size_t)255);
    return r;
  };
  char*  zstart = p;                       // bcur|gcnt|pooled zeroed together
  int*   bcur   = (int*)  alloc(1024*4);
  int*   gcnt   = (int*)  alloc((size_t)G*4);
  float* pooled = (float*)alloc((size_t)G*HC*4);
  size_t zbytes = (size_t)(p - zstart);
  int*   sbase  = (int*)  alloc(1025*4);
  int*   offs   = (int*)  alloc((size_t)(N+1)*4);
  int*   srcs   = (int*)  alloc(((size_t)E + N)*4);
  size_t featASz = (size_t)N*HC*2;
  size_t bufSz   = (size_t)NB*CAP*4;       // fixed-capacity slots
  if (bufSz > featASz) featASz = bufSz;    // featA doubles as buf
  bf*    featA  = (bf*)   alloc(featASz);
  bf*    featB  = (bf*)   alloc((size_t)N*HC*2);
  float* asrc   = (float*)alloc((size_t)N*4*4);
  float* adst   = (float*)alloc((size_t)N*4*4);
  unsigned* buf = (unsigned*)featA;        // dead before aggregate1 writes featA
  (void)ws_size; (void)n_in; (void)out_size;

  hipMemsetAsync(zstart, 0, zbytes, stream);

  const int tpb = 256;
  const int TB  = 1024;
  k_bscatter<<<256, 256, 0, stream>>>(edge, E, NB, bcur, buf);
  k_bscan   <<<1, 1024, 0, stream>>>(bcur, NB, E, N, sbase, offs);
  k_bbuild  <<<NB, NPB, 0, stream>>>(buf, bcur, sbase, batch, N, offs, srcs, gcnt);

  const int nb = (N + 3) / 4;              // aggregate: 1 node per wave
  // layer 1: x -> featB ; aggregate featB -> featA (overwrites dead buf)
  k_transform<DIN, false><<<TB, tpb, 0, stream>>>(x, W1, as1, ad1, featB, asrc, adst, N);
  k_aggregate<false><<<nb, tpb, 0, stream>>>(offs, srcs, featB, asrc, adst, b1, featA, batch, pooled, N);
  // layer 2: featA -> featB ; aggregate featB -> pooled
  k_transform<HC, true><<<TB, tpb, 0, stream>>>(featA, W2, as2, ad2, featB, asrc, adst, N);
  k_aggregate<true><<<nb, tpb, 0, stream>>>(offs, srcs, featB, asrc, adst, b2, nullptr, batch, pooled, N);

  k_final<<<(G+255)/256, 256, 0, stream>>>(pooled, gcnt, guid, Wg, bg, Wu, bu, Wo, bo,
                                           (float*)d_out, G);
}

// Round 13
// 396.110 us; speedup vs baseline: 1.7763x; 1.0718x over previous
//
#include <hip/hip_runtime.h>
#include <hip/hip_bf16.h>

#define DIN 32
#define HC  64    // H*C
#define NPB 512   // nodes per bucket (dst >> 9)
#define CAP 20480 // fixed bucket capacity: E/NB=16384 expected, sigma~127 -> 32 sigma

using bf = __hip_bfloat16;
static __device__ __forceinline__ float b2f(bf v){ return __bfloat162float(v); }

// ---- fused: bucket-scatter (blocks < SB) || transform layer-1 ----------
// Stream-serial kernels cost their sum; these two are independent
// (scatter: edge -> buf/bcur ; tf1: x -> featB/asrc/adst), so run them as
// block-split halves of one dispatch. Scatter blocks first (start earliest).

template<int K>
__global__ void k_scatter_tf(const int* __restrict__ edge, int E, int NB,
                             int* __restrict__ bcur, unsigned* __restrict__ buf,
                             int SB,
                             const float* __restrict__ xin,
                             const float* __restrict__ W,
                             const float* __restrict__ a_s,
                             const float* __restrict__ a_d,
                             bf* __restrict__ feat,
                             float* __restrict__ asrc, float* __restrict__ adst, int N,
                             int TB){
  __shared__ int lcnt[1024];
  __shared__ int lcur[1024];
  int t = threadIdx.x;
  if ((int)blockIdx.x < SB){               // ---- scatter half ----
    int chunk = (E + SB - 1) / SB;
    int beg = blockIdx.x*chunk, end = min(E, beg + chunk);
    for (int i = t; i < NB; i += blockDim.x) lcnt[i] = 0;
    __syncthreads();
    for (int i = beg + t; i < end; i += blockDim.x)
      atomicAdd(&lcnt[edge[E + i] >> 9], 1);
    __syncthreads();
    for (int i = t; i < NB; i += blockDim.x){
      int c = lcnt[i];
      lcur[i] = i*CAP + (c ? atomicAdd(&bcur[i], c) : 0);
    }
    __syncthreads();
    for (int i = beg + t; i < end; i += blockDim.x){
      int sN = edge[i], d = edge[E + i];
      int pos = atomicAdd(&lcur[d >> 9], 1);
      buf[pos] = ((unsigned)sN << 9) | (unsigned)(d & 511);
    }
    return;
  }
  // ---- transform half (R8 v2: W column in VGPRs, x same-addr broadcast)
  int lane = t & 63, wid = t >> 6;
  float wreg[K];
  #pragma unroll
  for (int k = 0; k < K; k++) wreg[k] = W[k*HC + lane];
  float as_l = a_s[lane], ad_l = a_d[lane];
  int gw = (blockIdx.x - SB)*4 + wid;
  int nw = TB*4;
  for (int n = gw; n < N; n += nw){
    float acc = 0.f;
    const float* xr = xin + (size_t)n*K;
    #pragma unroll
    for (int k = 0; k < K; k += 4){
      float4 xv = *(const float4*)(xr + k);              // same-addr broadcast
      acc = fmaf(xv.x, wreg[k+0], acc);
      acc = fmaf(xv.y, wreg[k+1], acc);
      acc = fmaf(xv.z, wreg[k+2], acc);
      acc = fmaf(xv.w, wreg[k+3], acc);
    }
    feat[((size_t)n << 6) + lane] = __float2bfloat16(acc);
    float ps = acc*as_l, pd = acc*ad_l;
    #pragma unroll
    for (int d = 1; d < 16; d <<= 1){ ps += __shfl_xor(ps, d); pd += __shfl_xor(pd, d); }
    if ((lane & 15) == 0){
      asrc[n*4 + (lane>>4)] = ps;
      adst[n*4 + (lane>>4)] = pd;
    }
  }
}

// one block: exclusive scan of bucket fills -> srcs bases; totals.
__global__ void k_bscan(const int* __restrict__ bcur, int NB, int E, int N,
                        int* __restrict__ sbase, int* __restrict__ offs){
  __shared__ int s[1024];
  int t = threadIdx.x;
  int mine = (t < NB) ? min(bcur[t], CAP) : 0;
  s[t] = mine; __syncthreads();
  for (int d = 1; d < 1024; d <<= 1){
    int v = (t >= d) ? s[t-d] : 0;
    __syncthreads();
    s[t] += v;
    __syncthreads();
  }
  if (t < NB) sbase[t] = (s[t] - mine) + t*NPB;  // + self-loops of prior buckets
  if (t == 0) offs[N] = E + N;
}

// one block (512 thr) per bucket: local CSR in LDS; self-loop at slot 0.
__global__ void k_bbuild(const unsigned* __restrict__ buf, const int* __restrict__ bcur,
                         const int* __restrict__ sbase, const int* __restrict__ batch,
                         int N, int* __restrict__ offs, int* __restrict__ srcs,
                         int* __restrict__ gcnt){
  __shared__ int s[NPB];
  __shared__ int cur[NPB];
  int b = blockIdx.x, t = threadIdx.x;
  int base = b << 9;
  int nn = min(NPB, N - base);
  int sbeg = b*CAP;
  int send = sbeg + min(bcur[b], CAP);
  int sb = sbase[b];
  s[t] = (t < nn) ? 1 : 0;                 // self-loop seed
  __syncthreads();
  for (int i = sbeg + t; i < send; i += NPB)
    atomicAdd(&s[buf[i] & 511u], 1);
  __syncthreads();
  int c0 = s[t];
  __syncthreads();
  for (int d = 1; d < NPB; d <<= 1){
    int v = (t >= d) ? s[t-d] : 0;
    __syncthreads();
    s[t] += v;
    __syncthreads();
  }
  int start = s[t] - c0;
  if (t < nn){
    offs[base + t] = sb + start;
    srcs[sb + start] = base + t;           // self-loop
    cur[t] = start + 1;
    atomicAdd(&gcnt[batch[base + t]], 1);  // graph node count
  }
  __syncthreads();
  for (int i = sbeg + t; i < send; i += NPB){
    unsigned v = buf[i];
    int pos = atomicAdd(&cur[v & 511u], 1);
    srcs[sb + pos] = (int)(v >> 9);
  }
}

// standalone transform for layer 2 (bf16 input)
template<int K>
__global__ void k_transform(const bf* __restrict__ xin,
                            const float* __restrict__ W,
                            const float* __restrict__ a_s,
                            const float* __restrict__ a_d,
                            bf* __restrict__ feat,
                            float* __restrict__ asrc, float* __restrict__ adst, int N){
  int t = threadIdx.x, lane = t & 63, wid = t >> 6;
  float wreg[K];
  #pragma unroll
  for (int k = 0; k < K; k++) wreg[k] = W[k*HC + lane];
  float as_l = a_s[lane], ad_l = a_d[lane];
  int gw = blockIdx.x*4 + wid;
  int nw = gridDim.x*4;
  for (int n = gw; n < N; n += nw){
    float acc = 0.f;
    const bf* xr = xin + (size_t)n*K;
    #pragma unroll
    for (int k = 0; k < K; k += 8){
      uint4 d = *(const uint4*)(xr + k);                 // same-addr broadcast
      acc = fmaf(__int_as_float((int)(d.x << 16)),         wreg[k+0], acc);
      acc = fmaf(__int_as_float((int)(d.x & 0xffff0000u)), wreg[k+1], acc);
      acc = fmaf(__int_as_float((int)(d.y << 16)),         wreg[k+2], acc);
      acc = fmaf(__int_as_float((int)(d.y & 0xffff0000u)), wreg[k+3], acc);
      acc = fmaf(__int_as_float((int)(d.z << 16)),         wreg[k+4], acc);
      acc = fmaf(__int_as_float((int)(d.z & 0xffff0000u)), wreg[k+5], acc);
      acc = fmaf(__int_as_float((int)(d.w << 16)),         wreg[k+6], acc);
      acc = fmaf(__int_as_float((int)(d.w & 0xffff0000u)), wreg[k+7], acc);
    }
    feat[((size_t)n << 6) + lane] = __float2bfloat16(acc);
    float ps = acc*as_l, pd = acc*ad_l;
    #pragma unroll
    for (int d = 1; d < 16; d <<= 1){ ps += __shfl_xor(ps, d); pd += __shfl_xor(pd, d); }
    if ((lane & 15) == 0){
      asrc[n*4 + (lane>>4)] = ps;
      adst[n*4 + (lane>>4)] = pd;
    }
  }
}

// ---- softmax-aggregate v7: v6 + chunk-boundary software pipeline -------
// R12 arithmetic: ~90k issue-cycles vs 185k wall -> ~50% stall at chunk
// boundaries (srcs load -> dependent asrc gather -> exp, ~500-700 cyc
// serial). Prefetch chunk k+1's srcs AND its asrc gather during chunk k's
// phase B; vmcnt waits land after phase B. Wave-synchronous, no barriers.
// Memory pattern unchanged: 2 random 128-B segments per VMEM instr (R9
// law), 2 B/lane epilogue stores, FINAL pools via block LDS combine.

template<bool FINAL>
__global__ void k_aggregate(const int* __restrict__ offs, const int* __restrict__ srcs,
                            const bf* __restrict__ feat,
                            const float* __restrict__ asrc, const float* __restrict__ adst,
                            const float* __restrict__ bias,
                            bf* __restrict__ out,
                            const int* __restrict__ batch,
                            float* __restrict__ pooled, int N){
  __shared__ float2 lwh[4][4][66];         // [wave][head][edge slot(+pad)]
  __shared__ float red[4][HC];             // FINAL block combine
  int t = threadIdx.x, lane = t & 63, wid = t >> 6;
  int n = blockIdx.x*4 + wid;
  bool active = (n < N);
  if (!FINAL && !active) return;
  int ns = active ? n : (N-1);             // safe index for inactive tail waves
  int cl = lane & 31, half = lane >> 5, h2 = cl >> 3;
  const float4 adv = *(const float4*)(adst + (size_t)ns*4);
  int beg = offs[ns], end = offs[ns+1];
  float2 acc = make_float2(0.f, 0.f);
  float den = 0.f;
  const float2* lp = &lwh[wid][h2][half];
  const unsigned* featU = (const unsigned*)feat;   // uniform base + voffset
  // preamble: prefetch chunk 0
  int i0 = beg + lane;
  int sv = (i0 < end) ? srcs[i0] : 0;
  float4 av = *(const float4*)(asrc + (size_t)sv*4);
  for (int j0 = beg; j0 < end; j0 += 64){
    int m = end - j0; if (m > 64) m = 64;
    // phase A: exp + LDS publish (memory already in sv/av)
    float z = (lane < m) ? 1.f : 0.f;
    float e0 = av.x + adv.x; e0 = (e0>0.f)?e0:0.2f*e0;
    float e1 = av.y + adv.y; e1 = (e1>0.f)?e1:0.2f*e1;
    float e2 = av.z + adv.z; e2 = (e2>0.f)?e2:0.2f*e2;
    float e3 = av.w + adv.w; e3 = (e3>0.f)?e3:0.2f*e3;
    float ob = __int_as_float(sv << 5);    // dword row offset (row = 32 dwords)
    lwh[wid][0][lane] = make_float2(z*__expf(e0), ob);
    lwh[wid][1][lane] = make_float2(z*__expf(e1), ob);
    lwh[wid][2][lane] = make_float2(z*__expf(e2), ob);
    lwh[wid][3][lane] = make_float2(z*__expf(e3), ob);
    // prefetch chunk k+1 (wave-uniform condition)
    int nj = j0 + 64;
    int svn = 0;
    float4 avn = av;
    if (nj < end){
      int i1 = nj + lane;
      svn = (i1 < end) ? srcs[i1] : 0;
      avn = *(const float4*)(asrc + (size_t)svn*4);
    }
    // phase B: lane = (channel-pair, edge-half); 2 edges per iteration
    #pragma unroll 8
    for (int jj = 0; jj < m; jj += 2){
      float2 rec = lp[jj];                 // (w for my head, row offset bits)
      unsigned idx = (unsigned)__float_as_int(rec.y) | (unsigned)cl;
      unsigned d = featU[idx];
      acc.x = fmaf(rec.x, __int_as_float((int)(d << 16)),         acc.x);
      acc.y = fmaf(rec.x, __int_as_float((int)(d & 0xffff0000u)), acc.y);
      den += rec.x;
    }
    sv = svn; av = avn;
  }
  acc.x += __shfl_xor(acc.x, 32);
  acc.y += __shfl_xor(acc.y, 32);
  den   += __shfl_xor(den, 32);            // all 64 lanes now hold totals
  // spread: channel c = lane; source lane = lane>>1, pick x/y by parity
  float vx = __shfl(acc.x, lane >> 1);
  float vy = __shfl(acc.y, lane >> 1);
  float r = ((lane & 1) ? vy : vx)/den + bias[lane];
  r = (r > 0.f) ? r : expm1f(r);           // elu
  if (FINAL){
    red[wid][lane] = active ? r : 0.f;
    __syncthreads();
    if (wid == 0){
      int n0 = blockIdx.x*4;
      int g0 = batch[min(n0, N-1)];
      int g3 = batch[min(n0+3, N-1)];
      float s4 = red[0][lane] + red[1][lane] + red[2][lane] + red[3][lane];
      if (g0 == g3){                       // fast path (~96% of blocks)
        atomicAdd(&pooled[(size_t)g0*HC + lane], s4);
      } else {
        for (int w2 = 0; w2 < 4; w2++){
          int nw = n0 + w2;
          if (nw < N) atomicAdd(&pooled[(size_t)batch[nw]*HC + lane], red[w2][lane]);
        }
      }
    }
  } else {
    out[((size_t)n << 6) + lane] = __float2bfloat16(r);   // 2 B/lane store
  }
}

// ---- head: mean-pool already summed; MLPs. fp32 output -----------------

__global__ void k_final(const float* __restrict__ pooled, const int* __restrict__ gcnt,
                        const float* __restrict__ guid,
                        const float* __restrict__ Wg, const float* __restrict__ bg,
                        const float* __restrict__ Wu, const float* __restrict__ bu,
                        const float* __restrict__ Wo, const float* __restrict__ bo,
                        float* __restrict__ outp, int G){
  __shared__ float sWg[HC*16], sWo[16*7], sbg[16], sWu[16], sbu[16], sbo[7];
  int t = threadIdx.x;
  for (int i = t; i < HC*16; i += blockDim.x) sWg[i] = Wg[i];
  for (int i = t; i < 16*7;  i += blockDim.x) sWo[i] = Wo[i];
  if (t < 16){ sbg[t] = bg[t]; sWu[t] = Wu[t]; sbu[t] = bu[t]; }
  if (t < 7) sbo[t] = bo[t];
  __syncthreads();
  int g = blockIdx.x*blockDim.x + t;
  if (g >= G) return;
  float inv = 1.f / fmaxf((float)gcnt[g], 1.f);
  float v[16];
  #pragma unroll
  for (int j = 0; j < 16; j++) v[j] = sbg[j];
  for (int c = 0; c < HC; c++){
    float pc = pooled[g*HC + c] * inv;
    #pragma unroll
    for (int j = 0; j < 16; j++) v[j] = fmaf(pc, sWg[c*16 + j], v[j]);
  }
  float gd = guid[g];
  #pragma unroll
  for (int j = 0; j < 16; j++){
    float u = fmaf(gd, sWu[j], sbu[j]);
    v[j] += (u > 0.f) ? u : 0.f;
  }
  #pragma unroll
  for (int k = 0; k < 7; k++){
    float o = sbo[k];
    #pragma unroll
    for (int j = 0; j < 16; j++) o = fmaf(v[j], sWo[j*7 + k], o);
    outp[g*7 + k] = o;
  }
}

// ---- launch ------------------------------------------------------------

extern "C" void kernel_launch(void* const* d_in, const int* in_sizes, int n_in,
                              void* d_out, int out_size, void* d_ws, size_t ws_size,
                              hipStream_t stream){
  const float* x    = (const float*)d_in[0];
  const int*   edge = (const int*)d_in[1];
  const int*   batch= (const int*)d_in[2];
  const float* guid = (const float*)d_in[3];
  const float* W1   = (const float*)d_in[4];
  const float* as1  = (const float*)d_in[5];
  const float* ad1  = (const float*)d_in[6];
  const float* b1   = (const float*)d_in[7];
  const float* W2   = (const float*)d_in[8];
  const float* as2  = (const float*)d_in[9];
  const float* ad2  = (const float*)d_in[10];
  const float* b2   = (const float*)d_in[11];
  const float* Wg   = (const float*)d_in[12];
  const float* bg   = (const float*)d_in[13];
  const float* Wu   = (const float*)d_in[14];
  const float* bu   = (const float*)d_in[15];
  const float* Wo   = (const float*)d_in[16];
  const float* bo   = (const float*)d_in[17];

  const int N = in_sizes[0] / DIN;
  const int E = in_sizes[1] / 2;
  const int G = in_sizes[3];
  const int NB = (N + NPB - 1) >> 9;

  char* p = (char*)d_ws;
  auto alloc = [&](size_t nbytes)->void*{
    void* r = (void*)p;
    p += ((nbytes + 255) & ~(size_t)255);
    return r;
  };
  char*  zstart = p;                       // bcur|gcnt|pooled zeroed together
  int*   bcur   = (int*)  alloc(1024*4);
  int*   gcnt   = (int*)  alloc((size_t)G*4);
  float* pooled = (float*)alloc((size_t)G*HC*4);
  size_t zbytes = (size_t)(p - zstart);
  int*   sbase  = (int*)  alloc(1025*4);
  int*   offs   = (int*)  alloc((size_t)(N+1)*4);
  int*   srcs   = (int*)  alloc(((size_t)E + N)*4);
  size_t featASz = (size_t)N*HC*2;
  size_t bufSz   = (size_t)NB*CAP*4;       // fixed-capacity slots
  if (bufSz > featASz) featASz = bufSz;    // featA doubles as buf
  bf*    featA  = (bf*)   alloc(featASz);
  bf*    featB  = (bf*)   alloc((size_t)N*HC*2);
  float* asrc   = (float*)alloc((size_t)N*4*4);
  float* adst   = (float*)alloc((size_t)N*4*4);
  unsigned* buf = (unsigned*)featA;        // dead before aggregate1 writes featA
  (void)ws_size; (void)n_in; (void)out_size;

  hipMemsetAsync(zstart, 0, zbytes, stream);

  const int tpb = 256;
  const int SB  = 256;                     // scatter blocks
  const int TB  = 1024;                    // transform blocks
  // fused: scatter edge->buf  ||  tf1 x->featB
  k_scatter_tf<DIN><<<SB + TB, tpb, 0, stream>>>(
      edge, E, NB, bcur, buf, SB, x, W1, as1, ad1, featB, asrc, adst, N, TB);
  k_bscan <<<1, 1024, 0, stream>>>(bcur, NB, E, N, sbase, offs);
  k_bbuild<<<NB, NPB, 0, stream>>>(buf, bcur, sbase, batch, N, offs, srcs, gcnt);

  const int nb = (N + 3) / 4;              // aggregate: 1 node per wave
  // layer 1: aggregate featB -> featA (overwrites dead buf)
  k_aggregate<false><<<nb, tpb, 0, stream>>>(offs, srcs, featB, asrc, adst, b1, featA, batch, pooled, N);
  // layer 2: featA -> featB ; aggregate featB -> pooled
  k_transform<HC><<<TB, tpb, 0, stream>>>(featA, W2, as2, ad2, featB, asrc, adst, N);
  k_aggregate<true><<<nb, tpb, 0, stream>>>(offs, srcs, featB, asrc, adst, b2, nullptr, batch, pooled, N);

  k_final<<<(G+255)/256, 256, 0, stream>>>(pooled, gcnt, guid, Wg, bg, Wu, bu, Wo, bo,
                                           (float*)d_out, G);
}